// Round 6
// baseline (747.915 us; speedup 1.0000x reference)
//
#include <hip/hip_runtime.h>

// BilinearAttention B=8, N=2048, H=1024 — MFMA f16-split pipeline, v7:
// 128x128 tile / 4 waves / 64KB LDS -> TWO blocks per CU. Independent
// co-resident blocks cover each other's ds_read bursts and vmcnt drains
// (the v4-v6 256x256 single-block convoy was the 47% MfmaUtil ceiling).
//
// Global plane-grouped format for all GEMM operands: rows of 128-byte groups,
// group g covers k=[g*32,g*32+32) as [32 hi f16 | 32 lo f16]  (split operands)
// or k=[g*64,g*64+64) as [64 f16]                             (plain f16 operands).
// Every matrix here has a 4096-byte row stride and 32 k-groups.
//
//   prep_v : value fp32 -> Vp planes [b][n][g][hi|lo]  +  Vt f16 [b][h][n]
//   prep_w : W fp32 [k][n] -> Wtp planes [n][g][hi|lo]
//   prep_q : query fp32 -> Qp planes [b*m][g][hi|lo]   (parked in attn region)
//   gemm<1>: interP = split(Qp) @ Wtp   (3-MFMA split) -> planes in out region
//   gemm<2>: logits = relu(interP @ Vp^T) masked -> attn fp32
//   softmax: rowwise in place + f16 copy attnH (parked in dead Vp region)
//   gemm<3>: out = attnH @ Vt  (plain f16 MFMA)

typedef _Float16 half8 __attribute__((ext_vector_type(8)));
typedef float f32x4 __attribute__((ext_vector_type(4)));
typedef unsigned short u16;
typedef unsigned int u32;

#define BATCH 8
#define SEQ   2048
#define HID   1024
#define MINV  (-1e9f)

#define AS1 __attribute__((address_space(1)))
#define AS3 __attribute__((address_space(3)))

__device__ __forceinline__ u16 h2u(_Float16 h) { return __builtin_bit_cast(u16, h); }

// split fp32 -> (hi,lo) f16 packed into one u32 (hi in low half)
__device__ __forceinline__ u32 packhl(float x) {
    _Float16 h = (_Float16)x;
    _Float16 l = (_Float16)(x - (float)h);
    return (u32)h2u(h) | ((u32)h2u(l) << 16);
}

__device__ __forceinline__ void gload16(const char* g, AS3 char* l) {
    __builtin_amdgcn_global_load_lds((const AS1 void*)g, (AS3 void*)l, 16, 0, 0);
}

// ---------------------------------------------------------------------------
// prep_v: 64x64 tiles. Writes Vp (plane-grouped) coalesced and Vt (f16,
// transposed to [b][h][n]) via LDS transpose.
// ---------------------------------------------------------------------------
__global__ __launch_bounds__(256) void prep_v(const float* __restrict__ V,
                                              u16* __restrict__ Vp,
                                              u16* __restrict__ Vt)
{
    __shared__ __align__(16) u16 lt[64 * 72];
    const int b = blockIdx.z, n0 = blockIdx.y * 64, h0 = blockIdx.x * 64;
    const int t = threadIdx.x;
    const int r = t >> 4, c4 = (t & 15) * 4;
#pragma unroll
    for (int it = 0; it < 4; ++it) {
        const int rr = r + it * 16;
        const float4 x = *(const float4*)(V + ((size_t)b * SEQ + n0 + rr) * HID + h0 + c4);
        const float xs[4] = {x.x, x.y, x.z, x.w};
        u32 p[4];
#pragma unroll
        for (int e = 0; e < 4; ++e) {
            p[e] = packhl(xs[e]);
            lt[(c4 + e) * 72 + rr] = (u16)p[e];
        }
        const int g = (h0 + c4) >> 5, j = c4 & 31;
        u16* base = Vp + (((size_t)b * SEQ + n0 + rr) * 32 + g) * 64;
        *(uint2*)(base + j) = make_uint2((p[0] & 0xffffu) | (p[1] << 16),
                                         (p[2] & 0xffffu) | (p[3] << 16));
        *(uint2*)(base + 32 + j) = make_uint2((p[0] >> 16) | (p[1] & 0xffff0000u),
                                              (p[2] >> 16) | (p[3] & 0xffff0000u));
    }
    __syncthreads();
    const int hr = t >> 2, cc = (t & 3) * 2;
    uint4 v0 = *(const uint4*)&lt[hr * 72 + cc * 8];
    uint4 v1 = *(const uint4*)&lt[hr * 72 + cc * 8 + 8];
    u16* dst = Vt + ((size_t)b * HID + h0 + hr) * SEQ + n0 + cc * 8;
    *(uint4*)dst = v0;
    *(uint4*)(dst + 8) = v1;
}

// ---------------------------------------------------------------------------
// prep_w: W [k][n] fp32 -> Wtp planes [n][g][hi|lo], 64x64 LDS transpose.
// ---------------------------------------------------------------------------
__global__ __launch_bounds__(256) void prep_w(const float* __restrict__ W,
                                              u16* __restrict__ Wtp)
{
    __shared__ __align__(16) u32 lt[64 * 68];
    const int n0 = blockIdx.x * 64, k0 = blockIdx.y * 64;
    const int t = threadIdx.x;
    const int r = t >> 4, c4 = (t & 15) * 4;
#pragma unroll
    for (int it = 0; it < 4; ++it) {
        const int rr = r + it * 16;
        const float4 x = *(const float4*)(W + (size_t)(k0 + rr) * HID + n0 + c4);
        const float xs[4] = {x.x, x.y, x.z, x.w};
#pragma unroll
        for (int e = 0; e < 4; ++e) lt[(c4 + e) * 68 + rr] = packhl(xs[e]);
    }
    __syncthreads();
    const int n = t >> 2;
#pragma unroll
    for (int s = 0; s < 4; ++s) {
        const int ci = (t & 3) + s * 4;
        uint4 v = *(const uint4*)&lt[n * 68 + ci * 4];
        const int k = k0 + ci * 4;
        u16* base = Wtp + (((size_t)n0 + n) * 32 + (k >> 5)) * 64;
        const int j = k & 31;
        *(uint2*)(base + j) = make_uint2((v.x & 0xffffu) | (v.y << 16),
                                         (v.z & 0xffffu) | (v.w << 16));
        *(uint2*)(base + 32 + j) = make_uint2((v.x >> 16) | (v.y & 0xffff0000u),
                                              (v.z >> 16) | (v.w & 0xffff0000u));
    }
}

// ---------------------------------------------------------------------------
// prep_q: query fp32 [row][1024] -> Qp planes [row][g][hi|lo]. One block/row.
// ---------------------------------------------------------------------------
__global__ __launch_bounds__(256) void prep_q(const float* __restrict__ Q,
                                              u16* __restrict__ Qp)
{
    const size_t row = blockIdx.x;
    const int t = threadIdx.x;
    const float4 x = ((const float4*)(Q + row * HID))[t];
    const u32 p0 = packhl(x.x), p1 = packhl(x.y), p2 = packhl(x.z), p3 = packhl(x.w);
    const int k = t * 4;
    u16* base = Qp + (row * 32 + (k >> 5)) * 64;
    const int j = k & 31;
    *(uint2*)(base + j) = make_uint2((p0 & 0xffffu) | (p1 << 16),
                                     (p2 & 0xffffu) | (p3 << 16));
    *(uint2*)(base + 32 + j) = make_uint2((p0 >> 16) | (p1 & 0xffff0000u),
                                          (p2 >> 16) | (p3 & 0xffff0000u));
}

// ---------------------------------------------------------------------------
// MFMA cluster: 4 A-frags x 2 B-cols (split: 3 MFMAs/unit; plain: 2).
// ---------------------------------------------------------------------------
template <bool SPLIT>
__device__ __forceinline__ void cluster4x2(f32x4 (&acc)[4][4], int jb,
                                           const half8 (&ah)[4], const half8 (&al)[4],
                                           const half8 (&bh)[4], const half8 (&bl)[4])
{
#pragma unroll
    for (int f = 0; f < 4; ++f) {
#pragma unroll
        for (int jj = 0; jj < 2; ++jj) {
            const int j = jb + jj;
            f32x4 c = acc[f][j];
            if constexpr (SPLIT) {
                c = __builtin_amdgcn_mfma_f32_16x16x32_f16(al[f], bh[j], c, 0, 0, 0);
                c = __builtin_amdgcn_mfma_f32_16x16x32_f16(ah[f], bl[j], c, 0, 0, 0);
                c = __builtin_amdgcn_mfma_f32_16x16x32_f16(ah[f], bh[j], c, 0, 0, 0);
            } else {
                c = __builtin_amdgcn_mfma_f32_16x16x32_f16(ah[f], bh[j], c, 0, 0, 0);
                c = __builtin_amdgcn_mfma_f32_16x16x32_f16(al[f], bl[j], c, 0, 0, 0);
            }
            acc[f][j] = c;
        }
    }
}

#define SBAR() __builtin_amdgcn_sched_barrier(0)

// ---------------------------------------------------------------------------
// MFMA GEMM, 128x128 block tile, 4 waves (2m x 2n), double-buffered LDS
// (2 x 32KB = 64KB -> 2 blocks/CU). One vmcnt(0)+s_barrier per K-step;
// counted lgkm 2-phase inside the step. Cross-block TLP (the co-resident
// block is never at the same phase) covers read bursts and the drain.
//
// Per K-step:
//   reads: A frags (8 b128) + B cols 0,1 (4)      [12 lgkm]
//   issue: 8 global_load_lds -> other buffer       (flight = whole step)
//   reads: B cols 2,3 (4)                          [16 lgkm total]
//   lgkmcnt(4) -> P0 = A x B01 ; lgkmcnt(0) -> P1 = A x B23
//   vmcnt(0) + s_barrier (buffer swap protection)
//
// Within-row offsets XOR-swizzled by (row&7)<<4 on BOTH the per-lane global
// source and the ds_read address (involution -> consistent, conflict-free).
// ds_reads use hoisted base + compile-time immediate offsets (no in-loop
// address VALU).
// MODE 1: A,B split planes, C plane-grouped out        [gemm1]
// MODE 2: A,B split planes, relu+mask epilogue, C fp32 [gemm2]
// MODE 3: A,B plain f16 (64 k/group), C fp32           [gemm3]
// ---------------------------------------------------------------------------
template <int MODE>
__global__ __launch_bounds__(256, 2) void gemm_mfma(
    const char* __restrict__ Abase, const char* __restrict__ Bbase,
    void* __restrict__ Cbase, const int* __restrict__ Mbase,
    int ldc, long sAb, long sBb, long sC, long sM)
{
    constexpr bool SPLIT = (MODE != 3);
    extern __shared__ __align__(16) char smem[];   // 2 x (A 16KB | B 16KB)

    // bijective XCD-aware block swizzle (all grids have nwg % 8 == 0)
    const int nx = gridDim.x, ny = gridDim.y;
    const int nxy = nx * ny;
    int wg = blockIdx.x + nx * (blockIdx.y + ny * blockIdx.z);
    const int cpx = (nxy * gridDim.z) >> 3;
    wg = (wg & 7) * cpx + (wg >> 3);
    const int bz = wg / nxy;
    const int rem = wg - bz * nxy;
    const int m0 = (rem / nx) * 128, n0 = (rem % nx) * 128;

    const int tid = threadIdx.x;
    const int w = tid >> 6, l = tid & 63;
    const int wm = w >> 1, wn = w & 1;            // 2 x 2 wave grid -> 64x64/wave
    const int lm = l & 15, q = l >> 4;

    const char* Ab = Abase + (long)bz * sAb;
    const char* Bb = Bbase + (long)bz * sBb;

    // staging offsets (k-invariant): LDS slot -> inverse-swizzled global
    u32 aoffs[4], boffs[4];
    int dsto[4];
#pragma unroll
    for (int it = 0; it < 4; ++it) {
        const int off = it * 4096 + tid * 16;     // chunk it: rows [it*32, it*32+32)
        dsto[it] = off;
        const int row = off >> 7;
        const int swi = (off & 127) ^ ((row & 7) << 4);
        aoffs[it] = (u32)(m0 + row) * 4096u + (u32)swi;
        boffs[it] = (u32)(n0 + row) * 4096u + (u32)swi;
    }
    // fragment-read swizzled within-row offset (row&7 == lm&7 for all frags)
    const int wofs = (q * 16) ^ ((lm & 7) << 4);

    f32x4 acc[4][4];
#pragma unroll
    for (int i = 0; i < 4; ++i)
#pragma unroll
        for (int j = 0; j < 4; ++j) acc[i][j] = (f32x4){0.f, 0.f, 0.f, 0.f};

    AS3 char* lds = (AS3 char*)smem;

    // prologue: stage K-step 0 into buf 0 (drained at loop top)
#pragma unroll
    for (int it = 0; it < 4; ++it) gload16(Ab + aoffs[it], lds + dsto[it]);
#pragma unroll
    for (int it = 0; it < 4; ++it) gload16(Bb + boffs[it], lds + 16384 + dsto[it]);

    half8 ah[4], al[4], bh[4], bl[4];

    for (int ks = 0; ks < 32; ++ks) {
        const int cur = ks & 1;
        const char* At = smem + cur * 32768;
        const char* Bt = At + 16384;
        AS3 char* ldsA = lds + (cur ^ 1) * 32768;
        AS3 char* ldsB = ldsA + 16384;
        const u32 kb = (u32)(ks + 1) * 128u;

        // single sync point: own gloads drained + all waves past last step's
        // reads -> buf[cur] resident, buf[cur^1] safe to overwrite.
        asm volatile("s_waitcnt vmcnt(0)" ::: "memory");
        __builtin_amdgcn_s_barrier();
        SBAR();

        // ---- reads: A frags (8) + B cols 0,1 (4); hoisted bases + imm offs ----
        {
            const char* arp = At + (wm * 64 + lm) * 128 + wofs;
            const char* alp = At + (wm * 64 + lm) * 128 + (wofs ^ 64);
#pragma unroll
            for (int i = 0; i < 4; ++i) {
                ah[i] = *(const half8*)(arp + i * 2048);
                al[i] = *(const half8*)(alp + i * 2048);
            }
            const char* brp = Bt + (wn * 64 + lm) * 128 + wofs;
            const char* blp = Bt + (wn * 64 + lm) * 128 + (wofs ^ 64);
            bh[0] = *(const half8*)(brp);
            bl[0] = *(const half8*)(blp);
            bh[1] = *(const half8*)(brp + 2048);
            bl[1] = *(const half8*)(blp + 2048);
            // ---- stage next K-step (flight = whole step; other block covers) ----
            if (ks < 31) {
#pragma unroll
                for (int it = 0; it < 4; ++it) gload16(Ab + (aoffs[it] + kb), ldsA + dsto[it]);
#pragma unroll
                for (int it = 0; it < 4; ++it) gload16(Bb + (boffs[it] + kb), ldsB + dsto[it]);
            }
            // ---- reads: B cols 2,3 (4) ----
            bh[2] = *(const half8*)(brp + 2 * 2048);
            bl[2] = *(const half8*)(blp + 2 * 2048);
            bh[3] = *(const half8*)(brp + 3 * 2048);
            bl[3] = *(const half8*)(blp + 3 * 2048);
        }

        // ---- P0: A x B01 (B23 reads drain underneath) ----
        asm volatile("s_waitcnt lgkmcnt(4)" ::: "memory");
        SBAR();
        __builtin_amdgcn_s_setprio(1);
        cluster4x2<SPLIT>(acc, 0, ah, al, bh, bl);
        __builtin_amdgcn_s_setprio(0);

        // ---- P1: A x B23 ----
        asm volatile("s_waitcnt lgkmcnt(0)" ::: "memory");
        SBAR();
        __builtin_amdgcn_s_setprio(1);
        cluster4x2<SPLIT>(acc, 2, ah, al, bh, bl);
        __builtin_amdgcn_s_setprio(0);
        SBAR();
    }

    // ---- epilogue ----  C/D map: col = lane&15, row = (lane>>4)*4 + reg
#pragma unroll
    for (int i = 0; i < 4; ++i) {
        const int arow = wm * 64 + i * 16 + q * 4;
#pragma unroll
        for (int r = 0; r < 4; ++r) {
            const int grow = m0 + arow + r;
#pragma unroll
            for (int j = 0; j < 4; ++j) {
                const int gcol = n0 + wn * 64 + j * 16 + lm;
                const float v = acc[i][j][r];
                if constexpr (MODE == 1) {
                    const u32 p = packhl(v);
                    u16* base = (u16*)Cbase + ((size_t)grow * (ldc >> 5) + (gcol >> 5)) * 64;
                    base[gcol & 31] = (u16)p;
                    base[32 + (gcol & 31)] = (u16)(p >> 16);
                } else if constexpr (MODE == 2) {
                    const int mv = Mbase[(long)bz * sM + (long)grow * ldc + gcol];
                    ((float*)Cbase)[(long)bz * sC + (long)grow * ldc + gcol] =
                        (mv > 0) ? fmaxf(v, 0.f) : MINV;
                } else {
                    ((float*)Cbase)[(long)bz * sC + (long)grow * ldc + gcol] = v;
                }
            }
        }
    }
}

// ---------------------------------------------------------------------------
// Row softmax over 2048 elements, in place + f16 copy for gemm3.
// ---------------------------------------------------------------------------
__global__ __launch_bounds__(256) void softmax2048(float* __restrict__ attn,
                                                   u16* __restrict__ attnH)
{
    const long row = blockIdx.x;
    float* p = attn + row * 2048;
    const int tid = threadIdx.x;

    float4 v0 = ((const float4*)p)[tid];
    float4 v1 = ((const float4*)p)[tid + 256];

    float mx = fmaxf(fmaxf(fmaxf(v0.x, v0.y), fmaxf(v0.z, v0.w)),
                     fmaxf(fmaxf(v1.x, v1.y), fmaxf(v1.z, v1.w)));
#pragma unroll
    for (int o = 32; o >= 1; o >>= 1)
        mx = fmaxf(mx, __shfl_xor(mx, o, 64));

    __shared__ float redm[4];
    __shared__ float reds[4];
    const int wid = tid >> 6, lane = tid & 63;
    if (lane == 0) redm[wid] = mx;
    __syncthreads();
    mx = fmaxf(fmaxf(redm[0], redm[1]), fmaxf(redm[2], redm[3]));

    float e[8];
    e[0] = __expf(v0.x - mx); e[1] = __expf(v0.y - mx);
    e[2] = __expf(v0.z - mx); e[3] = __expf(v0.w - mx);
    e[4] = __expf(v1.x - mx); e[5] = __expf(v1.y - mx);
    e[6] = __expf(v1.z - mx); e[7] = __expf(v1.w - mx);

    float s = ((e[0] + e[1]) + (e[2] + e[3])) + ((e[4] + e[5]) + (e[6] + e[7]));
#pragma unroll
    for (int o = 32; o >= 1; o >>= 1)
        s += __shfl_xor(s, o, 64);
    if (lane == 0) reds[wid] = s;
    __syncthreads();
    s = (reds[0] + reds[1]) + (reds[2] + reds[3]);

    const float inv = 1.0f / s;
    float o0 = e[0] * inv, o1 = e[1] * inv, o2 = e[2] * inv, o3 = e[3] * inv;
    float o4 = e[4] * inv, o5 = e[5] * inv, o6 = e[6] * inv, o7 = e[7] * inv;
    ((float4*)p)[tid]       = make_float4(o0, o1, o2, o3);
    ((float4*)p)[tid + 256] = make_float4(o4, o5, o6, o7);

    u16* ph = attnH + row * 2048;
    ((uint2*)ph)[tid] =
        make_uint2((u32)h2u((_Float16)o0) | ((u32)h2u((_Float16)o1) << 16),
                   (u32)h2u((_Float16)o2) | ((u32)h2u((_Float16)o3) << 16));
    ((uint2*)ph)[tid + 256] =
        make_uint2((u32)h2u((_Float16)o4) | ((u32)h2u((_Float16)o5) << 16),
                   (u32)h2u((_Float16)o6) | ((u32)h2u((_Float16)o7) << 16));
}

extern "C" void kernel_launch(void* const* d_in, const int* in_sizes, int n_in,
                              void* d_out, int out_size, void* d_ws, size_t ws_size,
                              hipStream_t stream)
{
    (void)in_sizes; (void)n_in; (void)out_size; (void)ws_size;

    const float* query = (const float*)d_in[0];  // B,N,H
    const float* value = (const float*)d_in[1];  // B,N,H
    const int*   mask  = (const int*)d_in[2];    // B,N,N
    const float* W     = (const float*)d_in[3];  // H,H

    float* out  = (float*)d_out;                           // B*N*H
    float* attn = out + (size_t)BATCH * SEQ * HID;         // B*N*N

    // workspace: Vp 64MB | Vt 32MB | Wtp 4MB   (100MB total)
    u16* Vp  = (u16*)d_ws;
    u16* Vt  = (u16*)((char*)d_ws + ((size_t)64 << 20));
    u16* Wtp = (u16*)((char*)d_ws + ((size_t)96 << 20));

    // region reuse (stream-ordered, no overlap in time):
    u16* interP = (u16*)d_out;   // out region; dead once gemm3 writes out
    u16* Qp     = (u16*)attn;    // attn region; dead once gemm2 writes attn
    u16* attnH  = Vp;            // Vp region;  dead once gemm2 completes

    static int attr_done = 0;
    if (!attr_done) {
        hipFuncSetAttribute((const void*)gemm_mfma<1>,
                            hipFuncAttributeMaxDynamicSharedMemorySize, 65536);
        hipFuncSetAttribute((const void*)gemm_mfma<2>,
                            hipFuncAttributeMaxDynamicSharedMemorySize, 65536);
        hipFuncSetAttribute((const void*)gemm_mfma<3>,
                            hipFuncAttributeMaxDynamicSharedMemorySize, 65536);
        attr_done = 1;
    }

    prep_v<<<dim3(HID / 64, SEQ / 64, BATCH), 256, 0, stream>>>(value, Vp, Vt);
    prep_w<<<dim3(HID / 64, HID / 64, 1), 256, 0, stream>>>(W, Wtp);
    prep_q<<<dim3(BATCH * SEQ), 256, 0, stream>>>(query, Qp);

    // gemm1: interP = split(Qp) @ Wtp^T   M=16384 N=1024 K=1024
    gemm_mfma<1><<<dim3(HID / 128, (BATCH * SEQ) / 128, 1), 256, 65536, stream>>>(
        (const char*)Qp, (const char*)Wtp, interP, nullptr,
        HID, 0, 0, 0, 0);

    // gemm2: logits = relu(interP @ Vp^T) masked -> attn (fp32)
    gemm_mfma<2><<<dim3(SEQ / 128, SEQ / 128, BATCH), 256, 65536, stream>>>(
        (const char*)interP, (const char*)Vp, attn, mask,
        SEQ, (long)SEQ * 4096, (long)SEQ * 4096, (long)SEQ * SEQ, (long)SEQ * SEQ);

    softmax2048<<<dim3(BATCH * SEQ), 256, 0, stream>>>(attn, attnH);

    // gemm3: out = attnH @ Vt   M=2048 N=1024 K=2048 (plain f16, 64 k/group)
    gemm_mfma<3><<<dim3(HID / 128, SEQ / 128, BATCH), 256, 65536, stream>>>(
        (const char*)attnH, (const char*)Vt, out, nullptr,
        HID, (long)SEQ * 4096, (long)HID * 4096, (long)SEQ * HID, 0);
}

// Round 7
// 725.053 us; speedup vs baseline: 1.0315x; 1.0315x over previous
//
#include <hip/hip_runtime.h>

// BilinearAttention B=8, N=2048, H=1024 — MFMA f16-split pipeline, v8:
// v5 skeleton (256x256, 8 waves, double-buffered LDS, one vmcnt(0)+barrier
// per K-step, counted lgkm) + COHORT ANTI-PHASE ROTATION: even waves run
// quadrants Q0->Q1->Q2->Q3, odd waves Q2->Q3->Q0->Q1. Quadrants touch
// disjoint accumulators, so per-wave order is free (numerics identical);
// the two cohorts keep the LDS-read pipe and MFMA pipe simultaneously fed
// instead of the whole-CU read-burst/MFMA-burst convoy.
//
// Global plane-grouped format for all GEMM operands: rows of 128-byte groups,
// group g covers k=[g*32,g*32+32) as [32 hi f16 | 32 lo f16]  (split operands)
// or k=[g*64,g*64+64) as [64 f16]                             (plain f16 operands).
// Every matrix here has a 4096-byte row stride and 32 k-groups.
//
//   prep_v : value fp32 -> Vp planes [b][n][g][hi|lo]  +  Vt f16 [b][h][n]
//   prep_w : W fp32 [k][n] -> Wtp planes [n][g][hi|lo]
//   prep_q : query fp32 -> Qp planes [b*m][g][hi|lo]   (parked in attn region)
//   gemm<1>: interP = split(Qp) @ Wtp   (3-MFMA split) -> planes in out region
//   gemm<2>: logits = relu(interP @ Vp^T) masked -> attn fp32
//   softmax: rowwise in place + f16 copy attnH (parked in dead Vp region)
//   gemm<3>: out = attnH @ Vt  (plain f16 MFMA)

typedef _Float16 half8 __attribute__((ext_vector_type(8)));
typedef float f32x4 __attribute__((ext_vector_type(4)));
typedef unsigned short u16;
typedef unsigned int u32;

#define BATCH 8
#define SEQ   2048
#define HID   1024
#define MINV  (-1e9f)

#define AS1 __attribute__((address_space(1)))
#define AS3 __attribute__((address_space(3)))

__device__ __forceinline__ u16 h2u(_Float16 h) { return __builtin_bit_cast(u16, h); }

// split fp32 -> (hi,lo) f16 packed into one u32 (hi in low half)
__device__ __forceinline__ u32 packhl(float x) {
    _Float16 h = (_Float16)x;
    _Float16 l = (_Float16)(x - (float)h);
    return (u32)h2u(h) | ((u32)h2u(l) << 16);
}

__device__ __forceinline__ void gload16(const char* g, AS3 char* l) {
    __builtin_amdgcn_global_load_lds((const AS1 void*)g, (AS3 void*)l, 16, 0, 0);
}

// ---------------------------------------------------------------------------
// prep_v: 64x64 tiles. Writes Vp (plane-grouped) coalesced and Vt (f16,
// transposed to [b][h][n]) via LDS transpose.
// ---------------------------------------------------------------------------
__global__ __launch_bounds__(256) void prep_v(const float* __restrict__ V,
                                              u16* __restrict__ Vp,
                                              u16* __restrict__ Vt)
{
    __shared__ __align__(16) u16 lt[64 * 72];
    const int b = blockIdx.z, n0 = blockIdx.y * 64, h0 = blockIdx.x * 64;
    const int t = threadIdx.x;
    const int r = t >> 4, c4 = (t & 15) * 4;
#pragma unroll
    for (int it = 0; it < 4; ++it) {
        const int rr = r + it * 16;
        const float4 x = *(const float4*)(V + ((size_t)b * SEQ + n0 + rr) * HID + h0 + c4);
        const float xs[4] = {x.x, x.y, x.z, x.w};
        u32 p[4];
#pragma unroll
        for (int e = 0; e < 4; ++e) {
            p[e] = packhl(xs[e]);
            lt[(c4 + e) * 72 + rr] = (u16)p[e];
        }
        const int g = (h0 + c4) >> 5, j = c4 & 31;
        u16* base = Vp + (((size_t)b * SEQ + n0 + rr) * 32 + g) * 64;
        *(uint2*)(base + j) = make_uint2((p[0] & 0xffffu) | (p[1] << 16),
                                         (p[2] & 0xffffu) | (p[3] << 16));
        *(uint2*)(base + 32 + j) = make_uint2((p[0] >> 16) | (p[1] & 0xffff0000u),
                                              (p[2] >> 16) | (p[3] & 0xffff0000u));
    }
    __syncthreads();
    const int hr = t >> 2, cc = (t & 3) * 2;
    uint4 v0 = *(const uint4*)&lt[hr * 72 + cc * 8];
    uint4 v1 = *(const uint4*)&lt[hr * 72 + cc * 8 + 8];
    u16* dst = Vt + ((size_t)b * HID + h0 + hr) * SEQ + n0 + cc * 8;
    *(uint4*)dst = v0;
    *(uint4*)(dst + 8) = v1;
}

// ---------------------------------------------------------------------------
// prep_w: W [k][n] fp32 -> Wtp planes [n][g][hi|lo], 64x64 LDS transpose.
// ---------------------------------------------------------------------------
__global__ __launch_bounds__(256) void prep_w(const float* __restrict__ W,
                                              u16* __restrict__ Wtp)
{
    __shared__ __align__(16) u32 lt[64 * 68];
    const int n0 = blockIdx.x * 64, k0 = blockIdx.y * 64;
    const int t = threadIdx.x;
    const int r = t >> 4, c4 = (t & 15) * 4;
#pragma unroll
    for (int it = 0; it < 4; ++it) {
        const int rr = r + it * 16;
        const float4 x = *(const float4*)(W + (size_t)(k0 + rr) * HID + n0 + c4);
        const float xs[4] = {x.x, x.y, x.z, x.w};
#pragma unroll
        for (int e = 0; e < 4; ++e) lt[(c4 + e) * 68 + rr] = packhl(xs[e]);
    }
    __syncthreads();
    const int n = t >> 2;
#pragma unroll
    for (int s = 0; s < 4; ++s) {
        const int ci = (t & 3) + s * 4;
        uint4 v = *(const uint4*)&lt[n * 68 + ci * 4];
        const int k = k0 + ci * 4;
        u16* base = Wtp + (((size_t)n0 + n) * 32 + (k >> 5)) * 64;
        const int j = k & 31;
        *(uint2*)(base + j) = make_uint2((v.x & 0xffffu) | (v.y << 16),
                                         (v.z & 0xffffu) | (v.w << 16));
        *(uint2*)(base + 32 + j) = make_uint2((v.x >> 16) | (v.y & 0xffff0000u),
                                              (v.z >> 16) | (v.w & 0xffff0000u));
    }
}

// ---------------------------------------------------------------------------
// prep_q: query fp32 [row][1024] -> Qp planes [row][g][hi|lo]. One block/row.
// ---------------------------------------------------------------------------
__global__ __launch_bounds__(256) void prep_q(const float* __restrict__ Q,
                                              u16* __restrict__ Qp)
{
    const size_t row = blockIdx.x;
    const int t = threadIdx.x;
    const float4 x = ((const float4*)(Q + row * HID))[t];
    const u32 p0 = packhl(x.x), p1 = packhl(x.y), p2 = packhl(x.z), p3 = packhl(x.w);
    const int k = t * 4;
    u16* base = Qp + (row * 32 + (k >> 5)) * 64;
    const int j = k & 31;
    *(uint2*)(base + j) = make_uint2((p0 & 0xffffu) | (p1 << 16),
                                     (p2 & 0xffffu) | (p3 << 16));
    *(uint2*)(base + 32 + j) = make_uint2((p0 >> 16) | (p1 & 0xffff0000u),
                                          (p2 >> 16) | (p3 & 0xffff0000u));
}

// ---------------------------------------------------------------------------
// MFMA cluster: 4 A-frags x 2 B-cols (split: 3 MFMAs/unit; plain: 2).
// ---------------------------------------------------------------------------
template <bool SPLIT>
__device__ __forceinline__ void cluster4x2(f32x4 (&acc)[8][4], int ib, int jb,
                                           const half8 (&ah)[4], const half8 (&al)[4],
                                           half8 bh0, half8 bl0, half8 bh1, half8 bl1)
{
#pragma unroll
    for (int f = 0; f < 4; ++f) {
#pragma unroll
        for (int jj = 0; jj < 2; ++jj) {
            const half8 bh = jj ? bh1 : bh0;
            const half8 bl = jj ? bl1 : bl0;
            f32x4 c = acc[ib + f][jb + jj];
            if constexpr (SPLIT) {
                c = __builtin_amdgcn_mfma_f32_16x16x32_f16(al[f], bh, c, 0, 0, 0);
                c = __builtin_amdgcn_mfma_f32_16x16x32_f16(ah[f], bl, c, 0, 0, 0);
                c = __builtin_amdgcn_mfma_f32_16x16x32_f16(ah[f], bh, c, 0, 0, 0);
            } else {
                c = __builtin_amdgcn_mfma_f32_16x16x32_f16(ah[f], bh, c, 0, 0, 0);
                c = __builtin_amdgcn_mfma_f32_16x16x32_f16(al[f], bl, c, 0, 0, 0);
            }
            acc[ib + f][jb + jj] = c;
        }
    }
}

#define SBAR() __builtin_amdgcn_sched_barrier(0)

// ---------------------------------------------------------------------------
// Cohort K-loop. Quadrants: Q0=H0xG0(acc 0,0) Q1=H0xG1(acc 0,2)
// Q2=H1xG1(acc 4,2) Q3=H1xG0(acc 4,0). ROT=0: Q0,Q1,Q2,Q3 (reads H0,G0
// first). ROT=1: Q2,Q3,Q0,Q1 (reads H1,G1 first). Disjoint acc sets and
// unchanged per-acc MFMA chain order -> bitwise-identical results.
// Per step: 12 reads -> gloads -> 4 reads -> lgkm(4) QA -> lgkm(0) QB ->
// 8 reads (2nd A-half, regs reused) -> lgkm(0) QC,QD -> vmcnt(0)+barrier.
// ---------------------------------------------------------------------------
template <int MODE, int ROT>
__device__ __forceinline__ void kloop(
    const char* smem, AS3 char* lds,
    const char* __restrict__ Ab, const char* __restrict__ Bb,
    const u32 (&aoffs)[4], const u32 (&boffs)[4], const int (&dsto)[4],
    int wofs, int wm, int wn, int lm, f32x4 (&acc)[8][4])
{
    constexpr bool SPLIT = (MODE != 3);
    constexpr int FH = (ROT == 0) ? 0 : 128;      // first A-half row offset
    constexpr int SH = 128 - FH;                  // second A-half
    half8 ah[4], al[4];
    half8 b0h, b0l, b1h, b1l, b2h, b2l, b3h, b3l;

    for (int ks = 0; ks < 32; ++ks) {
        const int cur = ks & 1;
        const char* At = smem + cur * 65536;
        const char* Bt = At + 32768;
        AS3 char* ldsA = lds + (cur ^ 1) * 65536;
        AS3 char* ldsB = ldsA + 32768;
        const u32 kb = (u32)(ks + 1) * 128u;

        // single sync point: own gloads drained + all waves past last step's
        // reads -> buf[cur] resident, buf[cur^1] safe to overwrite.
        asm volatile("s_waitcnt vmcnt(0)" ::: "memory");
        __builtin_amdgcn_s_barrier();
        SBAR();

        // ---- reads: first A-half (8) + first B-group (4) ----
#pragma unroll
        for (int i = 0; i < 4; ++i) {
            const char* rp = At + (FH + (i >> 1) * 64 + wm * 32 + (i & 1) * 16 + lm) * 128;
            ah[i] = *(const half8*)(rp + wofs);
            al[i] = *(const half8*)(rp + (wofs ^ 64));
        }
        if constexpr (ROT == 0) {
            const char* cp0 = Bt + (wn * 32 + lm) * 128;
            b0h = *(const half8*)(cp0 + wofs);
            b0l = *(const half8*)(cp0 + (wofs ^ 64));
            const char* cp1 = Bt + (wn * 32 + 16 + lm) * 128;
            b1h = *(const half8*)(cp1 + wofs);
            b1l = *(const half8*)(cp1 + (wofs ^ 64));
        } else {
            const char* cp2 = Bt + (128 + wn * 32 + lm) * 128;
            b2h = *(const half8*)(cp2 + wofs);
            b2l = *(const half8*)(cp2 + (wofs ^ 64));
            const char* cp3 = Bt + (128 + wn * 32 + 16 + lm) * 128;
            b3h = *(const half8*)(cp3 + wofs);
            b3l = *(const half8*)(cp3 + (wofs ^ 64));
        }
        // ---- stage next K-step (flight = rest of step) ----
        if (ks < 31) {
#pragma unroll
            for (int it = 0; it < 4; ++it) gload16(Ab + (aoffs[it] + kb), ldsA + dsto[it]);
#pragma unroll
            for (int it = 0; it < 4; ++it) gload16(Bb + (boffs[it] + kb), ldsB + dsto[it]);
        }
        // ---- reads: second B-group (4) ----
        if constexpr (ROT == 0) {
            const char* cp2 = Bt + (128 + wn * 32 + lm) * 128;
            b2h = *(const half8*)(cp2 + wofs);
            b2l = *(const half8*)(cp2 + (wofs ^ 64));
            const char* cp3 = Bt + (128 + wn * 32 + 16 + lm) * 128;
            b3h = *(const half8*)(cp3 + wofs);
            b3l = *(const half8*)(cp3 + (wofs ^ 64));
        } else {
            const char* cp0 = Bt + (wn * 32 + lm) * 128;
            b0h = *(const half8*)(cp0 + wofs);
            b0l = *(const half8*)(cp0 + (wofs ^ 64));
            const char* cp1 = Bt + (wn * 32 + 16 + lm) * 128;
            b1h = *(const half8*)(cp1 + wofs);
            b1l = *(const half8*)(cp1 + (wofs ^ 64));
        }

        // ---- QA: first A-half x first B-group (2nd group drains under it) ----
        asm volatile("s_waitcnt lgkmcnt(4)" ::: "memory");
        SBAR();
        __builtin_amdgcn_s_setprio(1);
        if constexpr (ROT == 0) cluster4x2<SPLIT>(acc, 0, 0, ah, al, b0h, b0l, b1h, b1l);
        else                    cluster4x2<SPLIT>(acc, 4, 2, ah, al, b2h, b2l, b3h, b3l);
        __builtin_amdgcn_s_setprio(0);

        // ---- QB: first A-half x second B-group ----
        asm volatile("s_waitcnt lgkmcnt(0)" ::: "memory");
        SBAR();
        __builtin_amdgcn_s_setprio(1);
        if constexpr (ROT == 0) cluster4x2<SPLIT>(acc, 0, 2, ah, al, b2h, b2l, b3h, b3l);
        else                    cluster4x2<SPLIT>(acc, 4, 0, ah, al, b0h, b0l, b1h, b1l);
        __builtin_amdgcn_s_setprio(0);

        // ---- reads: second A-half (8, regs reused — first half dead) ----
#pragma unroll
        for (int i = 0; i < 4; ++i) {
            const char* rp = At + (SH + (i >> 1) * 64 + wm * 32 + (i & 1) * 16 + lm) * 128;
            ah[i] = *(const half8*)(rp + wofs);
            al[i] = *(const half8*)(rp + (wofs ^ 64));
        }
        // ---- QC + QD: second A-half x both B-groups (all regs) ----
        asm volatile("s_waitcnt lgkmcnt(0)" ::: "memory");
        SBAR();
        __builtin_amdgcn_s_setprio(1);
        if constexpr (ROT == 0) {
            cluster4x2<SPLIT>(acc, 4, 2, ah, al, b2h, b2l, b3h, b3l);
            cluster4x2<SPLIT>(acc, 4, 0, ah, al, b0h, b0l, b1h, b1l);
        } else {
            cluster4x2<SPLIT>(acc, 0, 0, ah, al, b0h, b0l, b1h, b1l);
            cluster4x2<SPLIT>(acc, 0, 2, ah, al, b2h, b2l, b3h, b3l);
        }
        __builtin_amdgcn_s_setprio(0);
        SBAR();
    }
}

// ---------------------------------------------------------------------------
// MFMA GEMM, 256x256 block tile, 8 waves (2m x 4n), double-buffered LDS
// (128KB). v5 sync skeleton + cohort anti-phase rotation (kloop<.,ROT>).
// Within-row offsets XOR-swizzled by (row&7)<<4 on BOTH the per-lane global
// source and the ds_read address (involution -> consistent, conflict-free).
// MODE 1: A,B split planes, C plane-grouped out        [gemm1]
// MODE 2: A,B split planes, relu+mask epilogue, C fp32 [gemm2]
// MODE 3: A,B plain f16 (64 k/group), C fp32           [gemm3]
// ---------------------------------------------------------------------------
template <int MODE>
__global__ __launch_bounds__(512, 2) void gemm_mfma(
    const char* __restrict__ Abase, const char* __restrict__ Bbase,
    void* __restrict__ Cbase, const int* __restrict__ Mbase,
    int ldc, long sAb, long sBb, long sC, long sM)
{
    extern __shared__ __align__(16) char smem[];   // 2 x (A 32KB | B 32KB)

    // bijective XCD-aware block swizzle (all grids have nwg % 8 == 0)
    const int nx = gridDim.x, ny = gridDim.y;
    const int nxy = nx * ny;
    int wg = blockIdx.x + nx * (blockIdx.y + ny * blockIdx.z);
    const int cpx = (nxy * gridDim.z) >> 3;
    wg = (wg & 7) * cpx + (wg >> 3);
    const int bz = wg / nxy;
    const int rem = wg - bz * nxy;
    const int m0 = (rem / nx) * 256, n0 = (rem % nx) * 256;

    const int tid = threadIdx.x;
    const int w = tid >> 6, l = tid & 63;
    const int wm = w >> 2, wn = w & 3;            // 2 x 4 wave grid
    const int lm = l & 15, q = l >> 4;

    const char* Ab = Abase + (long)bz * sAb;
    const char* Bb = Bbase + (long)bz * sBb;

    // staging offsets (k-invariant): LDS slot -> inverse-swizzled global
    u32 aoffs[4], boffs[4];
    int dsto[4];
#pragma unroll
    for (int it = 0; it < 4; ++it) {
        const int off = it * 8192 + tid * 16;     // chunk it: rows [it*64, it*64+64)
        dsto[it] = off;
        const int row = off >> 7;
        const int swi = (off & 127) ^ ((row & 7) << 4);
        aoffs[it] = (u32)(m0 + row) * 4096u + (u32)swi;
        boffs[it] = (u32)(n0 + row) * 4096u + (u32)swi;
    }
    // fragment-read swizzled within-row offset (row&7 == lm&7 for all frags)
    const int wofs = (q * 16) ^ ((lm & 7) << 4);

    f32x4 acc[8][4];
#pragma unroll
    for (int i = 0; i < 8; ++i)
#pragma unroll
        for (int j = 0; j < 4; ++j) acc[i][j] = (f32x4){0.f, 0.f, 0.f, 0.f};

    AS3 char* lds = (AS3 char*)smem;

    // prologue: stage K-step 0 into buf 0 (drained at loop top)
#pragma unroll
    for (int it = 0; it < 4; ++it) gload16(Ab + aoffs[it], lds + dsto[it]);
#pragma unroll
    for (int it = 0; it < 4; ++it) gload16(Bb + boffs[it], lds + 32768 + dsto[it]);

    if ((w & 1) == 0)
        kloop<MODE, 0>(smem, lds, Ab, Bb, aoffs, boffs, dsto, wofs, wm, wn, lm, acc);
    else
        kloop<MODE, 1>(smem, lds, Ab, Bb, aoffs, boffs, dsto, wofs, wm, wn, lm, acc);

    // ---- epilogue ----  C/D map: col = lane&15, row = (lane>>4)*4 + reg
#pragma unroll
    for (int i = 0; i < 8; ++i) {
        const int arow = (i >> 1) * 64 + wm * 32 + (i & 1) * 16 + q * 4;
#pragma unroll
        for (int r = 0; r < 4; ++r) {
            const int grow = m0 + arow + r;
#pragma unroll
            for (int j = 0; j < 4; ++j) {
                const int gcol = n0 + (j >> 1) * 128 + wn * 32 + (j & 1) * 16 + lm;
                const float v = acc[i][j][r];
                if constexpr (MODE == 1) {
                    const u32 p = packhl(v);
                    u16* base = (u16*)Cbase + ((size_t)grow * (ldc >> 5) + (gcol >> 5)) * 64;
                    base[gcol & 31] = (u16)p;
                    base[32 + (gcol & 31)] = (u16)(p >> 16);
                } else if constexpr (MODE == 2) {
                    const int mv = Mbase[(long)bz * sM + (long)grow * ldc + gcol];
                    ((float*)Cbase)[(long)bz * sC + (long)grow * ldc + gcol] =
                        (mv > 0) ? fmaxf(v, 0.f) : MINV;
                } else {
                    ((float*)Cbase)[(long)bz * sC + (long)grow * ldc + gcol] = v;
                }
            }
        }
    }
}

// ---------------------------------------------------------------------------
// Row softmax over 2048 elements, in place + f16 copy for gemm3.
// ---------------------------------------------------------------------------
__global__ __launch_bounds__(256) void softmax2048(float* __restrict__ attn,
                                                   u16* __restrict__ attnH)
{
    const long row = blockIdx.x;
    float* p = attn + row * 2048;
    const int tid = threadIdx.x;

    float4 v0 = ((const float4*)p)[tid];
    float4 v1 = ((const float4*)p)[tid + 256];

    float mx = fmaxf(fmaxf(fmaxf(v0.x, v0.y), fmaxf(v0.z, v0.w)),
                     fmaxf(fmaxf(v1.x, v1.y), fmaxf(v1.z, v1.w)));
#pragma unroll
    for (int o = 32; o >= 1; o >>= 1)
        mx = fmaxf(mx, __shfl_xor(mx, o, 64));

    __shared__ float redm[4];
    __shared__ float reds[4];
    const int wid = tid >> 6, lane = tid & 63;
    if (lane == 0) redm[wid] = mx;
    __syncthreads();
    mx = fmaxf(fmaxf(redm[0], redm[1]), fmaxf(redm[2], redm[3]));

    float e[8];
    e[0] = __expf(v0.x - mx); e[1] = __expf(v0.y - mx);
    e[2] = __expf(v0.z - mx); e[3] = __expf(v0.w - mx);
    e[4] = __expf(v1.x - mx); e[5] = __expf(v1.y - mx);
    e[6] = __expf(v1.z - mx); e[7] = __expf(v1.w - mx);

    float s = ((e[0] + e[1]) + (e[2] + e[3])) + ((e[4] + e[5]) + (e[6] + e[7]));
#pragma unroll
    for (int o = 32; o >= 1; o >>= 1)
        s += __shfl_xor(s, o, 64);
    if (lane == 0) reds[wid] = s;
    __syncthreads();
    s = (reds[0] + reds[1]) + (reds[2] + reds[3]);

    const float inv = 1.0f / s;
    float o0 = e[0] * inv, o1 = e[1] * inv, o2 = e[2] * inv, o3 = e[3] * inv;
    float o4 = e[4] * inv, o5 = e[5] * inv, o6 = e[6] * inv, o7 = e[7] * inv;
    ((float4*)p)[tid]       = make_float4(o0, o1, o2, o3);
    ((float4*)p)[tid + 256] = make_float4(o4, o5, o6, o7);

    u16* ph = attnH + row * 2048;
    ((uint2*)ph)[tid] =
        make_uint2((u32)h2u((_Float16)o0) | ((u32)h2u((_Float16)o1) << 16),
                   (u32)h2u((_Float16)o2) | ((u32)h2u((_Float16)o3) << 16));
    ((uint2*)ph)[tid + 256] =
        make_uint2((u32)h2u((_Float16)o4) | ((u32)h2u((_Float16)o5) << 16),
                   (u32)h2u((_Float16)o6) | ((u32)h2u((_Float16)o7) << 16));
}

extern "C" void kernel_launch(void* const* d_in, const int* in_sizes, int n_in,
                              void* d_out, int out_size, void* d_ws, size_t ws_size,
                              hipStream_t stream)
{
    (void)in_sizes; (void)n_in; (void)out_size; (void)ws_size;

    const float* query = (const float*)d_in[0];  // B,N,H
    const float* value = (const float*)d_in[1];  // B,N,H
    const int*   mask  = (const int*)d_in[2];    // B,N,N
    const float* W     = (const float*)d_in[3];  // H,H

    float* out  = (float*)d_out;                           // B*N*H
    float* attn = out + (size_t)BATCH * SEQ * HID;         // B*N*N

    // workspace: Vp 64MB | Vt 32MB | Wtp 4MB   (100MB total)
    u16* Vp  = (u16*)d_ws;
    u16* Vt  = (u16*)((char*)d_ws + ((size_t)64 << 20));
    u16* Wtp = (u16*)((char*)d_ws + ((size_t)96 << 20));

    // region reuse (stream-ordered, no overlap in time):
    u16* interP = (u16*)d_out;   // out region; dead once gemm3 writes out
    u16* Qp     = (u16*)attn;    // attn region; dead once gemm2 writes attn
    u16* attnH  = Vp;            // Vp region;  dead once gemm2 completes

    static int attr_done = 0;
    if (!attr_done) {
        hipFuncSetAttribute((const void*)gemm_mfma<1>,
                            hipFuncAttributeMaxDynamicSharedMemorySize, 131072);
        hipFuncSetAttribute((const void*)gemm_mfma<2>,
                            hipFuncAttributeMaxDynamicSharedMemorySize, 131072);
        hipFuncSetAttribute((const void*)gemm_mfma<3>,
                            hipFuncAttributeMaxDynamicSharedMemorySize, 131072);
        attr_done = 1;
    }

    prep_v<<<dim3(HID / 64, SEQ / 64, BATCH), 256, 0, stream>>>(value, Vp, Vt);
    prep_w<<<dim3(HID / 64, HID / 64, 1), 256, 0, stream>>>(W, Wtp);
    prep_q<<<dim3(BATCH * SEQ), 256, 0, stream>>>(query, Qp);

    // gemm1: interP = split(Qp) @ Wtp^T   M=16384 N=1024 K=1024
    gemm_mfma<1><<<dim3(HID / 256, (BATCH * SEQ) / 256, 1), 512, 131072, stream>>>(
        (const char*)Qp, (const char*)Wtp, interP, nullptr,
        HID, 0, 0, 0, 0);

    // gemm2: logits = relu(interP @ Vp^T) masked -> attn (fp32)
    gemm_mfma<2><<<dim3(SEQ / 256, SEQ / 256, BATCH), 512, 131072, stream>>>(
        (const char*)interP, (const char*)Vp, attn, mask,
        SEQ, (long)SEQ * 4096, (long)SEQ * 4096, (long)SEQ * SEQ, (long)SEQ * SEQ);

    softmax2048<<<dim3(BATCH * SEQ), 256, 0, stream>>>(attn, attnH);

    // gemm3: out = attnH @ Vt   M=2048 N=1024 K=2048 (plain f16, 64 k/group)
    gemm_mfma<3><<<dim3(HID / 256, SEQ / 256, BATCH), 512, 131072, stream>>>(
        (const char*)attnH, (const char*)Vt, out, nullptr,
        HID, (long)SEQ * 4096, (long)HID * 4096, (long)SEQ * HID, 0);
}

// Round 8
// 715.914 us; speedup vs baseline: 1.0447x; 1.0128x over previous
//
#include <hip/hip_runtime.h>

// BilinearAttention B=8, N=2048, H=1024 — MFMA f16-split pipeline, v9:
// v8 skeleton with (a) cohort anti-phase selector fixed to (w>>2)&1 so the
// two waves sharing a SIMD (w and w+4 under round-robin mapping) run
// opposite quadrant orders, (b) K-loop unrolled x2 with compile-time buffer
// bases -> all ds_reads are base+imm (no in-loop address VALU), (c) distinct
// kernel names per GEMM mode for profiling visibility.
//
// Global plane-grouped format: rows of 128-byte groups; group g covers
// k=[g*32,g*32+32) as [32 hi f16 | 32 lo f16] (split) or k=[g*64,g*64+64)
// as [64 f16] (plain). Row stride 4096 B, 32 k-groups everywhere.
//
//   prep_v : value fp32 -> Vp planes + Vt f16 [b][h][n]
//   prep_w : W fp32 [k][n] -> Wtp planes [n][g][hi|lo]
//   prep_q : query fp32 -> Qp planes (parked in attn region)
//   gemm1_qw : interP = split(Qp) @ Wtp  -> planes in out region
//   gemm2_av : logits = relu(interP @ Vp^T) masked -> attn fp32
//   softmax2048 : rowwise + f16 copy attnH (parked in dead Vp region)
//   gemm3_out : out = attnH @ Vt (plain f16)

typedef _Float16 half8 __attribute__((ext_vector_type(8)));
typedef float f32x4 __attribute__((ext_vector_type(4)));
typedef unsigned short u16;
typedef unsigned int u32;

#define BATCH 8
#define SEQ   2048
#define HID   1024
#define MINV  (-1e9f)

#define AS1 __attribute__((address_space(1)))
#define AS3 __attribute__((address_space(3)))

__device__ __forceinline__ u16 h2u(_Float16 h) { return __builtin_bit_cast(u16, h); }

__device__ __forceinline__ u32 packhl(float x) {
    _Float16 h = (_Float16)x;
    _Float16 l = (_Float16)(x - (float)h);
    return (u32)h2u(h) | ((u32)h2u(l) << 16);
}

__device__ __forceinline__ void gload16(const char* g, AS3 char* l) {
    __builtin_amdgcn_global_load_lds((const AS1 void*)g, (AS3 void*)l, 16, 0, 0);
}

// ---------------------------------------------------------------------------
__global__ __launch_bounds__(256) void prep_v(const float* __restrict__ V,
                                              u16* __restrict__ Vp,
                                              u16* __restrict__ Vt)
{
    __shared__ __align__(16) u16 lt[64 * 72];
    const int b = blockIdx.z, n0 = blockIdx.y * 64, h0 = blockIdx.x * 64;
    const int t = threadIdx.x;
    const int r = t >> 4, c4 = (t & 15) * 4;
#pragma unroll
    for (int it = 0; it < 4; ++it) {
        const int rr = r + it * 16;
        const float4 x = *(const float4*)(V + ((size_t)b * SEQ + n0 + rr) * HID + h0 + c4);
        const float xs[4] = {x.x, x.y, x.z, x.w};
        u32 p[4];
#pragma unroll
        for (int e = 0; e < 4; ++e) {
            p[e] = packhl(xs[e]);
            lt[(c4 + e) * 72 + rr] = (u16)p[e];
        }
        const int g = (h0 + c4) >> 5, j = c4 & 31;
        u16* base = Vp + (((size_t)b * SEQ + n0 + rr) * 32 + g) * 64;
        *(uint2*)(base + j) = make_uint2((p[0] & 0xffffu) | (p[1] << 16),
                                         (p[2] & 0xffffu) | (p[3] << 16));
        *(uint2*)(base + 32 + j) = make_uint2((p[0] >> 16) | (p[1] & 0xffff0000u),
                                              (p[2] >> 16) | (p[3] & 0xffff0000u));
    }
    __syncthreads();
    const int hr = t >> 2, cc = (t & 3) * 2;
    uint4 v0 = *(const uint4*)&lt[hr * 72 + cc * 8];
    uint4 v1 = *(const uint4*)&lt[hr * 72 + cc * 8 + 8];
    u16* dst = Vt + ((size_t)b * HID + h0 + hr) * SEQ + n0 + cc * 8;
    *(uint4*)dst = v0;
    *(uint4*)(dst + 8) = v1;
}

// ---------------------------------------------------------------------------
__global__ __launch_bounds__(256) void prep_w(const float* __restrict__ W,
                                              u16* __restrict__ Wtp)
{
    __shared__ __align__(16) u32 lt[64 * 68];
    const int n0 = blockIdx.x * 64, k0 = blockIdx.y * 64;
    const int t = threadIdx.x;
    const int r = t >> 4, c4 = (t & 15) * 4;
#pragma unroll
    for (int it = 0; it < 4; ++it) {
        const int rr = r + it * 16;
        const float4 x = *(const float4*)(W + (size_t)(k0 + rr) * HID + n0 + c4);
        const float xs[4] = {x.x, x.y, x.z, x.w};
#pragma unroll
        for (int e = 0; e < 4; ++e) lt[(c4 + e) * 68 + rr] = packhl(xs[e]);
    }
    __syncthreads();
    const int n = t >> 2;
#pragma unroll
    for (int s = 0; s < 4; ++s) {
        const int ci = (t & 3) + s * 4;
        uint4 v = *(const uint4*)&lt[n * 68 + ci * 4];
        const int k = k0 + ci * 4;
        u16* base = Wtp + (((size_t)n0 + n) * 32 + (k >> 5)) * 64;
        const int j = k & 31;
        *(uint2*)(base + j) = make_uint2((v.x & 0xffffu) | (v.y << 16),
                                         (v.z & 0xffffu) | (v.w << 16));
        *(uint2*)(base + 32 + j) = make_uint2((v.x >> 16) | (v.y & 0xffff0000u),
                                              (v.z >> 16) | (v.w & 0xffff0000u));
    }
}

// ---------------------------------------------------------------------------
__global__ __launch_bounds__(256) void prep_q(const float* __restrict__ Q,
                                              u16* __restrict__ Qp)
{
    const size_t row = blockIdx.x;
    const int t = threadIdx.x;
    const float4 x = ((const float4*)(Q + row * HID))[t];
    const u32 p0 = packhl(x.x), p1 = packhl(x.y), p2 = packhl(x.z), p3 = packhl(x.w);
    const int k = t * 4;
    u16* base = Qp + (row * 32 + (k >> 5)) * 64;
    const int j = k & 31;
    *(uint2*)(base + j) = make_uint2((p0 & 0xffffu) | (p1 << 16),
                                     (p2 & 0xffffu) | (p3 << 16));
    *(uint2*)(base + 32 + j) = make_uint2((p0 >> 16) | (p1 & 0xffff0000u),
                                          (p2 >> 16) | (p3 & 0xffff0000u));
}

// ---------------------------------------------------------------------------
// MFMA cluster: 4 A-frags x 2 B-cols (split: 3 MFMAs/unit; plain: 2).
// ---------------------------------------------------------------------------
template <bool SPLIT>
__device__ __forceinline__ void cluster4x2(f32x4 (&acc)[8][4], int ib, int jb,
                                           const half8 (&ah)[4], const half8 (&al)[4],
                                           half8 bh0, half8 bl0, half8 bh1, half8 bl1)
{
#pragma unroll
    for (int f = 0; f < 4; ++f) {
#pragma unroll
        for (int jj = 0; jj < 2; ++jj) {
            const half8 bh = jj ? bh1 : bh0;
            const half8 bl = jj ? bl1 : bl0;
            f32x4 c = acc[ib + f][jb + jj];
            if constexpr (SPLIT) {
                c = __builtin_amdgcn_mfma_f32_16x16x32_f16(al[f], bh, c, 0, 0, 0);
                c = __builtin_amdgcn_mfma_f32_16x16x32_f16(ah[f], bl, c, 0, 0, 0);
                c = __builtin_amdgcn_mfma_f32_16x16x32_f16(ah[f], bh, c, 0, 0, 0);
            } else {
                c = __builtin_amdgcn_mfma_f32_16x16x32_f16(ah[f], bh, c, 0, 0, 0);
                c = __builtin_amdgcn_mfma_f32_16x16x32_f16(al[f], bl, c, 0, 0, 0);
            }
            acc[ib + f][jb + jj] = c;
        }
    }
}

#define SBAR() __builtin_amdgcn_sched_barrier(0)

// ---------------------------------------------------------------------------
// One K-step (32 k). CUR = compile-time buffer index; all ds_reads fold to
// hoisted lane-base + compile-time immediate. Quadrant order by ROT:
// ROT0: Q(H0,G0) Q(H0,G1) Q(H1,G1) Q(H1,G0); ROT1: Q(H1,G1) Q(H1,G0)
// Q(H0,G0) Q(H0,G1). Disjoint acc quadrants + unchanged per-acc chain
// order -> numerics identical regardless of ROT.
// Byte offsets: A frag i in half FH: FH + (i>>1)*8192 + (i&1)*2048.
// B col pair base: G0=0, G1=16384 (cols within pair: +0, +2048).
// ---------------------------------------------------------------------------
template <int MODE, int ROT, int CUR>
__device__ __forceinline__ void kstep(
    const char* pAh, const char* pAl, const char* pBh, const char* pBl,
    AS3 char* lds,
    const char* __restrict__ Ab, const char* __restrict__ Bb,
    const u32 (&aoffs)[4], const u32 (&boffs)[4], const int (&dsto)[4],
    u32 kb, bool more, f32x4 (&acc)[8][4])
{
    constexpr bool SPLIT = (MODE != 3);
    constexpr int FH = (ROT == 0) ? 0 : 16384;     // first A-half byte offset
    constexpr int SH = 16384 - FH;
    constexpr int GF = (ROT == 0) ? 0 : 16384;     // first B-group byte offset
    constexpr int GS = 16384 - GF;
    constexpr int AQ1 = (ROT == 0) ? 0 : 4;        // acc row-base of first A-half
    constexpr int AQ2 = 4 - AQ1;
    constexpr int BQ1 = (ROT == 0) ? 0 : 2;        // acc col-base of first B-group
    constexpr int BQ2 = 2 - BQ1;
    AS3 char* ldsA = lds + (CUR ^ 1) * 65536;
    AS3 char* ldsB = ldsA + 32768;

    // single sync point: own gloads drained + all waves past last step's
    // reads -> buf[CUR] resident, buf[CUR^1] safe to overwrite.
    asm volatile("s_waitcnt vmcnt(0)" ::: "memory");
    __builtin_amdgcn_s_barrier();
    SBAR();

    half8 ah[4], al[4];
#pragma unroll
    for (int i = 0; i < 4; ++i) {
        const int off = FH + (i >> 1) * 8192 + (i & 1) * 2048;
        ah[i] = *(const half8*)(pAh + off);
        al[i] = *(const half8*)(pAl + off);
    }
    half8 bFh0 = *(const half8*)(pBh + GF);
    half8 bFl0 = *(const half8*)(pBl + GF);
    half8 bFh1 = *(const half8*)(pBh + GF + 2048);
    half8 bFl1 = *(const half8*)(pBl + GF + 2048);
    // stage next K-step into the other buffer (flight = rest of step)
    if (more) {
#pragma unroll
        for (int it = 0; it < 4; ++it) gload16(Ab + (aoffs[it] + kb), ldsA + dsto[it]);
#pragma unroll
        for (int it = 0; it < 4; ++it) gload16(Bb + (boffs[it] + kb), ldsB + dsto[it]);
    }
    half8 bSh0 = *(const half8*)(pBh + GS);
    half8 bSl0 = *(const half8*)(pBl + GS);
    half8 bSh1 = *(const half8*)(pBh + GS + 2048);
    half8 bSl1 = *(const half8*)(pBl + GS + 2048);

    // QA: first A-half x first B-group (second group drains underneath)
    asm volatile("s_waitcnt lgkmcnt(4)" ::: "memory");
    SBAR();
    __builtin_amdgcn_s_setprio(1);
    cluster4x2<SPLIT>(acc, AQ1, BQ1, ah, al, bFh0, bFl0, bFh1, bFl1);
    __builtin_amdgcn_s_setprio(0);

    // QB: first A-half x second B-group
    asm volatile("s_waitcnt lgkmcnt(0)" ::: "memory");
    SBAR();
    __builtin_amdgcn_s_setprio(1);
    cluster4x2<SPLIT>(acc, AQ1, BQ2, ah, al, bSh0, bSl0, bSh1, bSl1);
    __builtin_amdgcn_s_setprio(0);

    // reads: second A-half (regs reused, first half dead)
#pragma unroll
    for (int i = 0; i < 4; ++i) {
        const int off = SH + (i >> 1) * 8192 + (i & 1) * 2048;
        ah[i] = *(const half8*)(pAh + off);
        al[i] = *(const half8*)(pAl + off);
    }
    // QC + QD: second A-half x both B-groups (all regs)
    asm volatile("s_waitcnt lgkmcnt(0)" ::: "memory");
    SBAR();
    __builtin_amdgcn_s_setprio(1);
    cluster4x2<SPLIT>(acc, AQ2, BQ2, ah, al, bSh0, bSl0, bSh1, bSl1);
    cluster4x2<SPLIT>(acc, AQ2, BQ1, ah, al, bFh0, bFl0, bFh1, bFl1);
    __builtin_amdgcn_s_setprio(0);
    SBAR();
}

// ---------------------------------------------------------------------------
// GEMM body: 256x256 tile, 8 waves (2m x 4n), double-buffered 128KB LDS,
// one vmcnt(0)+barrier per K-step, counted lgkm, SIMD-anti-phase cohorts
// (selector (w>>2)&1: waves w and w+4 share a SIMD and get opposite ROT).
// XOR-swizzle (row&7)<<4 on both the staged global source and the ds_read
// address (involution). K-loop unrolled x2 (compile-time CUR).
// MODE 1: split planes in, plane-grouped out; MODE 2: split planes,
// relu+mask, fp32 out; MODE 3: plain f16 (64 k/group), fp32 out.
// ---------------------------------------------------------------------------
template <int MODE, int ROT>
__device__ __forceinline__ void kloop(
    char* smem, const char* __restrict__ Ab, const char* __restrict__ Bb,
    const u32 (&aoffs)[4], const u32 (&boffs)[4], const int (&dsto)[4],
    int baseAhi, int baseAlo, int baseBhi, int baseBlo, f32x4 (&acc)[8][4])
{
    AS3 char* lds = (AS3 char*)smem;
    const char* pA0h = smem + baseAhi;
    const char* pA0l = smem + baseAlo;
    const char* pB0h = smem + baseBhi;
    const char* pB0l = smem + baseBlo;
    const char* pA1h = pA0h + 65536;
    const char* pA1l = pA0l + 65536;
    const char* pB1h = pB0h + 65536;
    const char* pB1l = pB0l + 65536;

    for (int ks = 0; ks < 32; ks += 2) {
        const u32 kb0 = (u32)(ks + 1) * 128u;
        const u32 kb1 = (u32)(ks + 2) * 128u;
        kstep<MODE, ROT, 0>(pA0h, pA0l, pB0h, pB0l, lds, Ab, Bb,
                            aoffs, boffs, dsto, kb0, true, acc);
        kstep<MODE, ROT, 1>(pA1h, pA1l, pB1h, pB1l, lds, Ab, Bb,
                            aoffs, boffs, dsto, kb1, ks < 30, acc);
    }
}

template <int MODE>
__device__ __forceinline__ void gemm_body(
    char* smem,
    const char* __restrict__ Abase, const char* __restrict__ Bbase,
    void* __restrict__ Cbase, const int* __restrict__ Mbase,
    int ldc, long sAb, long sBb, long sC, long sM)
{
    // bijective XCD-aware block swizzle (all grids have nwg % 8 == 0)
    const int nx = gridDim.x, ny = gridDim.y;
    const int nxy = nx * ny;
    int wg = blockIdx.x + nx * (blockIdx.y + ny * blockIdx.z);
    const int cpx = (nxy * gridDim.z) >> 3;
    wg = (wg & 7) * cpx + (wg >> 3);
    const int bz = wg / nxy;
    const int rem = wg - bz * nxy;
    const int m0 = (rem / nx) * 256, n0 = (rem % nx) * 256;

    const int tid = threadIdx.x;
    const int w = tid >> 6, l = tid & 63;
    const int wm = w >> 2, wn = w & 3;            // 2 x 4 wave grid
    const int lm = l & 15, q = l >> 4;

    const char* Ab = Abase + (long)bz * sAb;
    const char* Bb = Bbase + (long)bz * sBb;

    // staging offsets (k-invariant): LDS slot -> inverse-swizzled global
    u32 aoffs[4], boffs[4];
    int dsto[4];
#pragma unroll
    for (int it = 0; it < 4; ++it) {
        const int off = it * 8192 + tid * 16;     // chunk it: rows [it*64, it*64+64)
        dsto[it] = off;
        const int row = off >> 7;
        const int swi = (off & 127) ^ ((row & 7) << 4);
        aoffs[it] = (u32)(m0 + row) * 4096u + (u32)swi;
        boffs[it] = (u32)(n0 + row) * 4096u + (u32)swi;
    }
    // fragment-read swizzled within-row offset (row&7 == lm&7 for all frags)
    const int wofs = (q * 16) ^ ((lm & 7) << 4);
    const int baseAhi = (wm * 32 + lm) * 128 + wofs;
    const int baseAlo = (wm * 32 + lm) * 128 + (wofs ^ 64);
    const int baseBhi = 32768 + (wn * 32 + lm) * 128 + wofs;
    const int baseBlo = 32768 + (wn * 32 + lm) * 128 + (wofs ^ 64);

    f32x4 acc[8][4];
#pragma unroll
    for (int i = 0; i < 8; ++i)
#pragma unroll
        for (int j = 0; j < 4; ++j) acc[i][j] = (f32x4){0.f, 0.f, 0.f, 0.f};

    AS3 char* lds = (AS3 char*)smem;

    // prologue: stage K-step 0 into buf 0 (drained at loop top)
#pragma unroll
    for (int it = 0; it < 4; ++it) gload16(Ab + aoffs[it], lds + dsto[it]);
#pragma unroll
    for (int it = 0; it < 4; ++it) gload16(Bb + boffs[it], lds + 32768 + dsto[it]);

    // SIMD-anti-phase cohorts: waves w and w+4 share a SIMD (round-robin
    // mapping) and run opposite quadrant orders.
    if (((w >> 2) & 1) == 0)
        kloop<MODE, 0>(smem, Ab, Bb, aoffs, boffs, dsto,
                       baseAhi, baseAlo, baseBhi, baseBlo, acc);
    else
        kloop<MODE, 1>(smem, Ab, Bb, aoffs, boffs, dsto,
                       baseAhi, baseAlo, baseBhi, baseBlo, acc);

    // ---- epilogue ----  C/D map: col = lane&15, row = (lane>>4)*4 + reg
#pragma unroll
    for (int i = 0; i < 8; ++i) {
        const int arow = (i >> 1) * 64 + wm * 32 + (i & 1) * 16 + q * 4;
#pragma unroll
        for (int r = 0; r < 4; ++r) {
            const int grow = m0 + arow + r;
#pragma unroll
            for (int j = 0; j < 4; ++j) {
                const int gcol = n0 + (j >> 1) * 128 + wn * 32 + (j & 1) * 16 + lm;
                const float v = acc[i][j][r];
                if constexpr (MODE == 1) {
                    const u32 p = packhl(v);
                    u16* base = (u16*)Cbase + ((size_t)grow * (ldc >> 5) + (gcol >> 5)) * 64;
                    base[gcol & 31] = (u16)p;
                    base[32 + (gcol & 31)] = (u16)(p >> 16);
                } else if constexpr (MODE == 2) {
                    const int mv = Mbase[(long)bz * sM + (long)grow * ldc + gcol];
                    ((float*)Cbase)[(long)bz * sC + (long)grow * ldc + gcol] =
                        (mv > 0) ? fmaxf(v, 0.f) : MINV;
                } else {
                    ((float*)Cbase)[(long)bz * sC + (long)grow * ldc + gcol] = v;
                }
            }
        }
    }
}

// distinct kernel names per mode (profiling visibility)
__global__ __launch_bounds__(512, 2) void gemm1_qw(
    const char* __restrict__ A, const char* __restrict__ B, void* __restrict__ C,
    const int* __restrict__ M, int ldc, long sAb, long sBb, long sC, long sM)
{
    extern __shared__ __align__(16) char smem[];
    gemm_body<1>(smem, A, B, C, M, ldc, sAb, sBb, sC, sM);
}
__global__ __launch_bounds__(512, 2) void gemm2_av(
    const char* __restrict__ A, const char* __restrict__ B, void* __restrict__ C,
    const int* __restrict__ M, int ldc, long sAb, long sBb, long sC, long sM)
{
    extern __shared__ __align__(16) char smem[];
    gemm_body<2>(smem, A, B, C, M, ldc, sAb, sBb, sC, sM);
}
__global__ __launch_bounds__(512, 2) void gemm3_out(
    const char* __restrict__ A, const char* __restrict__ B, void* __restrict__ C,
    const int* __restrict__ M, int ldc, long sAb, long sBb, long sC, long sM)
{
    extern __shared__ __align__(16) char smem[];
    gemm_body<3>(smem, A, B, C, M, ldc, sAb, sBb, sC, sM);
}

// ---------------------------------------------------------------------------
// Row softmax over 2048 elements, in place + f16 copy for gemm3.
// ---------------------------------------------------------------------------
__global__ __launch_bounds__(256) void softmax2048(float* __restrict__ attn,
                                                   u16* __restrict__ attnH)
{
    const long row = blockIdx.x;
    float* p = attn + row * 2048;
    const int tid = threadIdx.x;

    float4 v0 = ((const float4*)p)[tid];
    float4 v1 = ((const float4*)p)[tid + 256];

    float mx = fmaxf(fmaxf(fmaxf(v0.x, v0.y), fmaxf(v0.z, v0.w)),
                     fmaxf(fmaxf(v1.x, v1.y), fmaxf(v1.z, v1.w)));
#pragma unroll
    for (int o = 32; o >= 1; o >>= 1)
        mx = fmaxf(mx, __shfl_xor(mx, o, 64));

    __shared__ float redm[4];
    __shared__ float reds[4];
    const int wid = tid >> 6, lane = tid & 63;
    if (lane == 0) redm[wid] = mx;
    __syncthreads();
    mx = fmaxf(fmaxf(redm[0], redm[1]), fmaxf(redm[2], redm[3]));

    float e[8];
    e[0] = __expf(v0.x - mx); e[1] = __expf(v0.y - mx);
    e[2] = __expf(v0.z - mx); e[3] = __expf(v0.w - mx);
    e[4] = __expf(v1.x - mx); e[5] = __expf(v1.y - mx);
    e[6] = __expf(v1.z - mx); e[7] = __expf(v1.w - mx);

    float s = ((e[0] + e[1]) + (e[2] + e[3])) + ((e[4] + e[5]) + (e[6] + e[7]));
#pragma unroll
    for (int o = 32; o >= 1; o >>= 1)
        s += __shfl_xor(s, o, 64);
    if (lane == 0) reds[wid] = s;
    __syncthreads();
    s = (reds[0] + reds[1]) + (reds[2] + reds[3]);

    const float inv = 1.0f / s;
    float o0 = e[0] * inv, o1 = e[1] * inv, o2 = e[2] * inv, o3 = e[3] * inv;
    float o4 = e[4] * inv, o5 = e[5] * inv, o6 = e[6] * inv, o7 = e[7] * inv;
    ((float4*)p)[tid]       = make_float4(o0, o1, o2, o3);
    ((float4*)p)[tid + 256] = make_float4(o4, o5, o6, o7);

    u16* ph = attnH + row * 2048;
    ((uint2*)ph)[tid] =
        make_uint2((u32)h2u((_Float16)o0) | ((u32)h2u((_Float16)o1) << 16),
                   (u32)h2u((_Float16)o2) | ((u32)h2u((_Float16)o3) << 16));
    ((uint2*)ph)[tid + 256] =
        make_uint2((u32)h2u((_Float16)o4) | ((u32)h2u((_Float16)o5) << 16),
                   (u32)h2u((_Float16)o6) | ((u32)h2u((_Float16)o7) << 16));
}

extern "C" void kernel_launch(void* const* d_in, const int* in_sizes, int n_in,
                              void* d_out, int out_size, void* d_ws, size_t ws_size,
                              hipStream_t stream)
{
    (void)in_sizes; (void)n_in; (void)out_size; (void)ws_size;

    const float* query = (const float*)d_in[0];  // B,N,H
    const float* value = (const float*)d_in[1];  // B,N,H
    const int*   mask  = (const int*)d_in[2];    // B,N,N
    const float* W     = (const float*)d_in[3];  // H,H

    float* out  = (float*)d_out;                           // B*N*H
    float* attn = out + (size_t)BATCH * SEQ * HID;         // B*N*N

    // workspace: Vp 64MB | Vt 32MB | Wtp 4MB   (100MB total)
    u16* Vp  = (u16*)d_ws;
    u16* Vt  = (u16*)((char*)d_ws + ((size_t)64 << 20));
    u16* Wtp = (u16*)((char*)d_ws + ((size_t)96 << 20));

    // region reuse (stream-ordered, no overlap in time):
    u16* interP = (u16*)d_out;   // out region; dead once gemm3 writes out
    u16* Qp     = (u16*)attn;    // attn region; dead once gemm2 writes attn
    u16* attnH  = Vp;            // Vp region;  dead once gemm2 completes

    static int attr_done = 0;
    if (!attr_done) {
        hipFuncSetAttribute((const void*)gemm1_qw,
                            hipFuncAttributeMaxDynamicSharedMemorySize, 131072);
        hipFuncSetAttribute((const void*)gemm2_av,
                            hipFuncAttributeMaxDynamicSharedMemorySize, 131072);
        hipFuncSetAttribute((const void*)gemm3_out,
                            hipFuncAttributeMaxDynamicSharedMemorySize, 131072);
        attr_done = 1;
    }

    prep_v<<<dim3(HID / 64, SEQ / 64, BATCH), 256, 0, stream>>>(value, Vp, Vt);
    prep_w<<<dim3(HID / 64, HID / 64, 1), 256, 0, stream>>>(W, Wtp);
    prep_q<<<dim3(BATCH * SEQ), 256, 0, stream>>>(query, Qp);

    // gemm1: interP = split(Qp) @ Wtp^T   M=16384 N=1024 K=1024
    gemm1_qw<<<dim3(HID / 256, (BATCH * SEQ) / 256, 1), 512, 131072, stream>>>(
        (const char*)Qp, (const char*)Wtp, interP, nullptr,
        HID, 0, 0, 0, 0);

    // gemm2: logits = relu(interP @ Vp^T) masked -> attn (fp32)
    gemm2_av<<<dim3(SEQ / 256, SEQ / 256, BATCH), 512, 131072, stream>>>(
        (const char*)interP, (const char*)Vp, attn, mask,
        SEQ, (long)SEQ * 4096, (long)SEQ * 4096, (long)SEQ * SEQ, (long)SEQ * SEQ);

    softmax2048<<<dim3(BATCH * SEQ), 256, 0, stream>>>(attn, attnH);

    // gemm3: out = attnH @ Vt   M=2048 N=1024 K=2048 (plain f16, 64 k/group)
    gemm3_out<<<dim3(HID / 256, SEQ / 256, BATCH), 512, 131072, stream>>>(
        (const char*)attnH, (const char*)Vt, out, nullptr,
        HID, (long)SEQ * 4096, (long)HID * 4096, (long)SEQ * HID, 0);
}